// Round 1
// baseline (904.998 us; speedup 1.0000x reference)
//
#include <hip/hip_runtime.h>
#include <hip/hip_bf16.h>
#include <hip/hip_cooperative_groups.h>
#include <math.h>

namespace cg = cooperative_groups;

#define SEQL 2048
#define NB   4
#define HID  4096
#define DM   128
#define DIN  256
#define DST  16
#define HD   64
#define NH   4
#define CONV_DIM 288
#define DPROJ 552
#define MROWS (SEQL*NB)      // 8192
#define TCH 64
#define NCHUNK (SEQL/TCH)    // 32

typedef __attribute__((ext_vector_type(8))) short short8;
typedef __attribute__((ext_vector_type(4))) float f32x4;

__device__ __forceinline__ float siluf(float v){ return v / (1.f + expf(-v)); }
__device__ __forceinline__ float geluf(float v){ return 0.5f*v*(1.f + erff(v*0.70710678118654752f)); }
__device__ __forceinline__ float wave_sum(float v){
    #pragma unroll
    for (int o = 32; o > 0; o >>= 1) v += __shfl_xor(v, o, 64);
    return v;
}
__device__ __forceinline__ unsigned bfpack2(float a, float b){
    __hip_bfloat162 v = __float22bfloat162_rn(make_float2(a, b));
    return *reinterpret_cast<unsigned*>(&v);
}

// ---------------- prep: convert weights to bf16 (in_w padded 552->560 rows)
__global__ __launch_bounds__(256) void k_prep_w(const float* __restrict__ w_down,
    const float* __restrict__ w_up, const float* __restrict__ in_w,
    const float* __restrict__ out_w,
    __hip_bfloat16* __restrict__ wd, __hip_bfloat16* __restrict__ wu,
    __hip_bfloat16* __restrict__ wi, __hip_bfloat16* __restrict__ wo)
{
    int idx = blockIdx.x*256 + threadIdx.x;
    if (idx < 524288) { wd[idx] = __float2bfloat16(w_down[idx]); return; }
    idx -= 524288;
    if (idx < 524288) { wu[idx] = __float2bfloat16(w_up[idx]); return; }
    idx -= 524288;
    if (idx < 71680) { wi[idx] = (idx < 552*128) ? __float2bfloat16(in_w[idx]) : __float2bfloat16(0.f); return; }
    idx -= 71680;
    if (idx < 32768) { wo[idx] = __float2bfloat16(out_w[idx]); }
}

// ---------------- K1: down-proj MFMA, split-K x2, partial out
__global__ __launch_bounds__(256) void k_down_mfma(const float* __restrict__ x,
    const __hip_bfloat16* __restrict__ wbf, float* __restrict__ partial)
{
    __shared__ __align__(16) short Abuf[64][72];
    __shared__ __align__(16) short Wbuf[128][72];
    const int tid = threadIdx.x;
    const int m0 = blockIdx.x * 64;
    const int ks = blockIdx.y;
    const int b  = m0 >> 11, l0 = m0 & 2047;
    const int lane = tid & 63, wv = tid >> 6;
    const int fr = lane & 15, q = lane >> 4;
    f32x4 acc[8];
    #pragma unroll
    for (int i = 0; i < 8; ++i) acc[i] = (f32x4){0.f,0.f,0.f,0.f};

    const int arow = tid >> 2, aseg = tid & 3;   // A: 4 thr/row, 16 floats
    const int wrow = tid >> 1, wseg = tid & 1;   // W: 2 thr/row, 32 shorts

    for (int k0 = ks*2048; k0 < ks*2048 + 2048; k0 += 64) {
        const float4* ap = (const float4*)(x + (size_t)((l0 + arow)*NB + b)*HID + k0 + aseg*16);
        float4 f0 = ap[0], f1 = ap[1], f2 = ap[2], f3 = ap[3];
        const uint4* wp = (const uint4*)(wbf + (size_t)wrow*HID + k0 + wseg*32);
        uint4 w0 = wp[0], w1 = wp[1], w2 = wp[2], w3 = wp[3];
        uint4 pk0, pk1;
        pk0.x = bfpack2(f0.x,f0.y); pk0.y = bfpack2(f0.z,f0.w);
        pk0.z = bfpack2(f1.x,f1.y); pk0.w = bfpack2(f1.z,f1.w);
        pk1.x = bfpack2(f2.x,f2.y); pk1.y = bfpack2(f2.z,f2.w);
        pk1.z = bfpack2(f3.x,f3.y); pk1.w = bfpack2(f3.z,f3.w);
        uint4* adst = (uint4*)&Abuf[arow][aseg*16];
        adst[0] = pk0; adst[1] = pk1;
        uint4* wdst = (uint4*)&Wbuf[wrow][wseg*32];
        wdst[0] = w0; wdst[1] = w1; wdst[2] = w2; wdst[3] = w3;
        __syncthreads();
        #pragma unroll
        for (int kh = 0; kh < 2; ++kh) {
            short8 af = *reinterpret_cast<const short8*>(&Abuf[wv*16 + fr][kh*32 + q*8]);
            #pragma unroll
            for (int ns = 0; ns < 8; ++ns) {
                short8 bf = *reinterpret_cast<const short8*>(&Wbuf[ns*16 + fr][kh*32 + q*8]);
                acc[ns] = __builtin_amdgcn_mfma_f32_16x16x32_bf16(af, bf, acc[ns], 0, 0, 0);
            }
        }
        __syncthreads();
    }
    #pragma unroll
    for (int ns = 0; ns < 8; ++ns)
        #pragma unroll
        for (int r = 0; r < 4; ++r)
            partial[((size_t)ks*MROWS + m0 + wv*16 + q*4 + r)*DM + ns*16 + fr] = acc[ns][r];
}

// ---------------- K1b: partial reduce + bias + GELU -> xmid fp32 + u_bf
__global__ __launch_bounds__(256) void k_down_fix(const float* __restrict__ partial,
    const float* __restrict__ bias, float* __restrict__ xmid,
    __hip_bfloat16* __restrict__ ubf)
{
    size_t i4 = ((size_t)blockIdx.x*256 + threadIdx.x)*4;
    int n = (int)(i4 & (DM-1));
    float4 p0 = *(const float4*)&partial[i4];
    float4 p1 = *(const float4*)&partial[(size_t)MROWS*DM + i4];
    float4 bv = *(const float4*)&bias[n];
    float4 v;
    v.x = geluf(p0.x + p1.x + bv.x);
    v.y = geluf(p0.y + p1.y + bv.y);
    v.z = geluf(p0.z + p1.z + bv.z);
    v.w = geluf(p0.w + p1.w + bv.w);
    *(float4*)&xmid[i4] = v;
    uint2 pk; pk.x = bfpack2(v.x, v.y); pk.y = bfpack2(v.z, v.w);
    *(uint2*)&ubf[i4] = pk;
}

// ---------------- in-proj MFMA: zx = u(bf16) @ in_w(bf16)^T  (N padded to 560)
__global__ __launch_bounds__(256) void k_proj_in(const __hip_bfloat16* __restrict__ ubf,
    const __hip_bfloat16* __restrict__ wbf, float* __restrict__ zx)
{
    __shared__ __align__(16) short Abuf[64][136];
    __shared__ __align__(16) short Wbuf[80][136];
    const int tid = threadIdx.x;
    const int m0 = blockIdx.x*64;
    const int n0 = blockIdx.y*80;
    for (int i = tid; i < 64*16; i += 256) {
        int r = i >> 4, s = i & 15;
        *(uint4*)&Abuf[r][s*8] = *(const uint4*)&ubf[(size_t)(m0+r)*DM + s*8];
    }
    for (int i = tid; i < 80*16; i += 256) {
        int r = i >> 4, s = i & 15;
        *(uint4*)&Wbuf[r][s*8] = *(const uint4*)&wbf[(size_t)(n0+r)*DM + s*8];
    }
    __syncthreads();
    const int lane = tid & 63, wv = tid >> 6, fr = lane & 15, q = lane >> 4;
    f32x4 acc[5];
    #pragma unroll
    for (int i = 0; i < 5; ++i) acc[i] = (f32x4){0.f,0.f,0.f,0.f};
    #pragma unroll
    for (int kt = 0; kt < 4; ++kt) {
        short8 af = *reinterpret_cast<const short8*>(&Abuf[wv*16 + fr][kt*32 + q*8]);
        #pragma unroll
        for (int ns = 0; ns < 5; ++ns) {
            short8 bf = *reinterpret_cast<const short8*>(&Wbuf[ns*16 + fr][kt*32 + q*8]);
            acc[ns] = __builtin_amdgcn_mfma_f32_16x16x32_bf16(af, bf, acc[ns], 0, 0, 0);
        }
    }
    #pragma unroll
    for (int ns = 0; ns < 5; ++ns) {
        int n = n0 + ns*16 + fr;
        if (n < DPROJ) {
            #pragma unroll
            for (int r = 0; r < 4; ++r)
                zx[(size_t)(m0 + wv*16 + q*4 + r)*DPROJ + n] = acc[ns][r];
        }
    }
}

// ---------------- out-proj MFMA, pass-templated epilogue:
// PASS 0: write u_bf only (h never consumed)
// PASS 1: fuse xmid blend -> hc_bf directly (replaces k_prep_up + h2 roundtrip)
template<int PASS>
__global__ __launch_bounds__(256) void k_proj_out_t(const __hip_bfloat16* __restrict__ ynbf,
    const __hip_bfloat16* __restrict__ wbf, const float* __restrict__ xmid,
    const float* __restrict__ gate1,
    __hip_bfloat16* __restrict__ ubf, __hip_bfloat16* __restrict__ hcbf)
{
    __shared__ __align__(16) short Abuf[64][136];
    __shared__ __align__(16) short Wbuf[128][136];
    const int tid = threadIdx.x;
    const int m0 = blockIdx.x*64;
    const int lane = tid & 63, wv = tid >> 6, fr = lane & 15, q = lane >> 4;
    f32x4 acc[8];
    #pragma unroll
    for (int i = 0; i < 8; ++i) acc[i] = (f32x4){0.f,0.f,0.f,0.f};
    for (int kb = 0; kb < 2; ++kb) {
        if (kb) __syncthreads();
        for (int i = tid; i < 64*16; i += 256) {
            int r = i >> 4, s = i & 15;
            *(uint4*)&Abuf[r][s*8] = *(const uint4*)&ynbf[(size_t)(m0+r)*DIN + kb*128 + s*8];
        }
        for (int i = tid; i < 128*16; i += 256) {
            int r = i >> 4, s = i & 15;
            *(uint4*)&Wbuf[r][s*8] = *(const uint4*)&wbf[(size_t)r*DIN + kb*128 + s*8];
        }
        __syncthreads();
        #pragma unroll
        for (int kt = 0; kt < 4; ++kt) {
            short8 af = *reinterpret_cast<const short8*>(&Abuf[wv*16 + fr][kt*32 + q*8]);
            #pragma unroll
            for (int ns = 0; ns < 8; ++ns) {
                short8 bf = *reinterpret_cast<const short8*>(&Wbuf[ns*16 + fr][kt*32 + q*8]);
                acc[ns] = __builtin_amdgcn_mfma_f32_16x16x32_bf16(af, bf, acc[ns], 0, 0, 0);
            }
        }
    }
    float ca = 0.f, cb = 0.f;
    if (PASS == 1) {
        float al = 1.f / (1.f + expf(-gate1[0]));
        ca = 1.f + al; cb = 1.f - al;
    }
    #pragma unroll
    for (int ns = 0; ns < 8; ++ns)
        #pragma unroll
        for (int r = 0; r < 4; ++r) {
            int m = m0 + wv*16 + q*4 + r, n = ns*16 + fr;
            float v = acc[ns][r];
            if (PASS == 0) {
                ubf[(size_t)m*DM + n] = __float2bfloat16(v);
            } else {
                float xm = xmid[(size_t)m*DM + n];
                hcbf[(size_t)m*DM + n] = __float2bfloat16(ca*xm + cb*v);
            }
        }
}

// ---------------- up-proj MFMA + bias + residual + transpose store
__global__ __launch_bounds__(256) void k_up_mfma(const __hip_bfloat16* __restrict__ hc,
    const __hip_bfloat16* __restrict__ wbf, const float* __restrict__ b_up,
    const float* __restrict__ x, float* __restrict__ out)
{
    __shared__ __align__(16) short Abuf[64][136];
    __shared__ __align__(16) short Wbuf[128][136];
    const int tid = threadIdx.x;
    const int m0 = blockIdx.x*64;
    const int n0 = blockIdx.y*128;
    for (int i = tid; i < 64*16; i += 256) {
        int r = i >> 4, s = i & 15;
        *(uint4*)&Abuf[r][s*8] = *(const uint4*)&hc[(size_t)(m0+r)*DM + s*8];
    }
    for (int i = tid; i < 128*16; i += 256) {
        int r = i >> 4, s = i & 15;
        *(uint4*)&Wbuf[r][s*8] = *(const uint4*)&wbf[(size_t)(n0+r)*DM + s*8];
    }
    __syncthreads();
    const int lane = tid & 63, wv = tid >> 6, fr = lane & 15, q = lane >> 4;
    f32x4 acc[8];
    #pragma unroll
    for (int i = 0; i < 8; ++i) acc[i] = (f32x4){0.f,0.f,0.f,0.f};
    #pragma unroll
    for (int kt = 0; kt < 4; ++kt) {
        short8 af = *reinterpret_cast<const short8*>(&Abuf[wv*16 + fr][kt*32 + q*8]);
        #pragma unroll
        for (int ns = 0; ns < 8; ++ns) {
            short8 bf = *reinterpret_cast<const short8*>(&Wbuf[ns*16 + fr][kt*32 + q*8]);
            acc[ns] = __builtin_amdgcn_mfma_f32_16x16x32_bf16(af, bf, acc[ns], 0, 0, 0);
        }
    }
    #pragma unroll
    for (int r = 0; r < 4; ++r) {
        int m = m0 + wv*16 + q*4 + r;
        int b = m >> 11, l = m & 2047;
        size_t rowbase = (size_t)(l*NB + b)*HID + n0;
        #pragma unroll
        for (int ns = 0; ns < 8; ++ns) {
            int n = ns*16 + fr;
            out[rowbase + n] = acc[ns][r] + b_up[n0 + n] + x[rowbase + n];
        }
    }
}

// ---------------- K3: causal depthwise conv7 + bias + silu
__global__ __launch_bounds__(256) void k_conv(const float* __restrict__ zx,
    const float* __restrict__ cw, const float* __restrict__ cb,
    float* __restrict__ xBC)
{
    int idx = blockIdx.x*256 + threadIdx.x;
    if (idx >= MROWS*CONV_DIM) return;
    int c = idx % CONV_DIM;
    int m = idx / CONV_DIM;
    int l = m & 2047, b = m >> 11;
    float acc = cb[c];
    #pragma unroll
    for (int k = 0; k < 7; ++k) {
        int l2 = l - 6 + k;
        if (l2 >= 0)
            acc = fmaf(zx[(size_t)(b*SEQL + l2)*DPROJ + DIN + c], cw[c*7 + k], acc);
    }
    xBC[(size_t)m*CONV_DIM + c] = siluf(acc);
}

// ---------------- K4 fused (cooperative): chunk states -> grid sync ->
//                  register-pipelined combine -> grid sync -> replay + emit y.
// 1024 blocks x 64 threads, ~25KB LDS/block -> 6 blocks/CU fit, 4/CU needed.
// LDS tiles (dA/Xs/Bs/Cs) persist across grid syncs: phase C reloads NOTHING.
__global__ __launch_bounds__(64) void k_scan_fused(const float* __restrict__ zx,
    const float* __restrict__ xBC, const float* __restrict__ dt_bias,
    const float* __restrict__ A_log, float* __restrict__ Sbuf,
    float* __restrict__ Pbuf, float* __restrict__ Hbuf,
    float* __restrict__ yfw, float* __restrict__ ybw)
{
    const int bid = blockIdx.x;
    const int c   = bid & (NCHUNK-1);
    const int h   = (bid >> 5) & (NH-1);
    const int b   = (bid >> 7) & 3;
    const int dir = bid >> 9;
    const int tid = threadIdx.x;
    __shared__ float dA_s[TCH], dt_s[TCH];
    __shared__ float Xs[TCH][HD];
    __shared__ float Bs[TCH][DST];
    __shared__ float Cs[TCH][DST];
    {
        const int kk = tid;
        const int l = dir ? (SEQL-1 - (c*TCH + kk)) : (c*TCH + kk);
        float dtraw = zx[(size_t)(b*SEQL + l)*DPROJ + 544 + dir*NH + h] + dt_bias[h];
        float dt = dtraw > 20.f ? dtraw : log1pf(expf(dtraw));
        dt_s[kk] = dt;
        dA_s[kk] = expf(dt * (-expf(A_log[h])));
    }
    __syncthreads();
    // X: 64 rows x 64 floats; float4/lane -> 4 rows/iter, fully coalesced
    #pragma unroll
    for (int t = 0; t < 16; ++t) {
        int k2 = t*4 + (tid >> 4);
        int p4 = (tid & 15)*4;
        int l2 = dir ? (SEQL-1 - (c*TCH + k2)) : (c*TCH + k2);
        float4 v = *(const float4*)&xBC[(size_t)(b*SEQL + l2)*CONV_DIM + h*HD + p4];
        float sc = dt_s[k2];
        v.x *= sc; v.y *= sc; v.z *= sc; v.w *= sc;
        *(float4*)&Xs[k2][p4] = v;
    }
    // B and C: 16 floats/row; float4/lane -> 16 rows/iter
    #pragma unroll
    for (int t = 0; t < 4; ++t) {
        int k2 = t*16 + (tid >> 2);
        int n4 = (tid & 3)*4;
        int l2 = dir ? (SEQL-1 - (c*TCH + k2)) : (c*TCH + k2);
        *(float4*)&Bs[k2][n4] = *(const float4*)&xBC[(size_t)(b*SEQL + l2)*CONV_DIM + DIN + n4];
        *(float4*)&Cs[k2][n4] = *(const float4*)&xBC[(size_t)(b*SEQL + l2)*CONV_DIM + DIN + DST + n4];
    }
    __syncthreads();
    const int pg = tid >> 2, ng = tid & 3;
    float s[4][4];
    #pragma unroll
    for (int i = 0; i < 4; ++i)
        #pragma unroll
        for (int j = 0; j < 4; ++j) s[i][j] = 0.f;
    for (int k2 = 0; k2 < TCH; ++k2) {
        float dAv = dA_s[k2];
        float4 xv = *(const float4*)&Xs[k2][pg*4];
        float4 bv = *(const float4*)&Bs[k2][ng*4];
        float xa[4] = {xv.x, xv.y, xv.z, xv.w};
        float ba[4] = {bv.x, bv.y, bv.z, bv.w};
        #pragma unroll
        for (int i = 0; i < 4; ++i)
            #pragma unroll
            for (int j = 0; j < 4; ++j)
                s[i][j] = fmaf(dAv, s[i][j], xa[i]*ba[j]);
    }
    const size_t sb = (size_t)bid * 1024;
    #pragma unroll
    for (int i = 0; i < 4; ++i) {
        float4 v = {s[i][0], s[i][1], s[i][2], s[i][3]};
        *(float4*)&Sbuf[sb + (size_t)((pg*4+i)*16 + ng*4)] = v;
    }
    {   // parallel chunk-decay product (was serial 64-iter on lane 0)
        float pv = dA_s[tid];
        #pragma unroll
        for (int o = 32; o > 0; o >>= 1) pv *= __shfl_xor(pv, o, 64);
        if (tid == 0) Pbuf[bid] = pv;
    }
    cg::this_grid().sync();
    // -------- phase B: combine. 32768 chains over 512 blocks; all 32 loads
    // issued up-front (independent addresses), then register fma chain.
    {
        const int gt = bid*64 + tid;
        if (gt < 32*1024) {
            const int g = gt >> 10, e = gt & 1023;
            float sv[NCHUNK], pw[NCHUNK];
            #pragma unroll
            for (int cc = 0; cc < NCHUNK; ++cc)
                sv[cc] = Sbuf[(size_t)(g*NCHUNK + cc)*1024 + e];
            #pragma unroll
            for (int cc = 0; cc < NCHUNK; ++cc)
                pw[cc] = Pbuf[g*NCHUNK + cc];
            float carry = 0.f;
            #pragma unroll
            for (int cc = 0; cc < NCHUNK; ++cc) {
                Hbuf[(size_t)(g*NCHUNK + cc)*1024 + e] = carry;
                carry = fmaf(pw[cc], carry, sv[cc]);
            }
        }
    }
    cg::this_grid().sync();
    // -------- phase C: replay from Hbuf init using LDS tiles still resident
    #pragma unroll
    for (int i = 0; i < 4; ++i) {
        float4 v = *(const float4*)&Hbuf[sb + (size_t)((pg*4+i)*16 + ng*4)];
        s[i][0] = v.x; s[i][1] = v.y; s[i][2] = v.z; s[i][3] = v.w;
    }
    float* yout = dir ? ybw : yfw;
    for (int k2 = 0; k2 < TCH; ++k2) {
        float dAv = dA_s[k2];
        float4 xv = *(const float4*)&Xs[k2][pg*4];
        float4 bv = *(const float4*)&Bs[k2][ng*4];
        float4 cv = *(const float4*)&Cs[k2][ng*4];
        float xa[4] = {xv.x, xv.y, xv.z, xv.w};
        float ba[4] = {bv.x, bv.y, bv.z, bv.w};
        float ca[4] = {cv.x, cv.y, cv.z, cv.w};
        float y[4];
        #pragma unroll
        for (int i = 0; i < 4; ++i) {
            #pragma unroll
            for (int j = 0; j < 4; ++j)
                s[i][j] = fmaf(dAv, s[i][j], xa[i]*ba[j]);
            y[i] = s[i][0]*ca[0] + s[i][1]*ca[1] + s[i][2]*ca[2] + s[i][3]*ca[3];
        }
        #pragma unroll
        for (int i = 0; i < 4; ++i) {
            y[i] += __shfl_xor(y[i], 1, 64);
            y[i] += __shfl_xor(y[i], 2, 64);
        }
        if (ng == 0) {
            int l2 = dir ? (SEQL-1 - (c*TCH + k2)) : (c*TCH + k2);
            float4 v = {y[0], y[1], y[2], y[3]};
            *(float4*)&yout[(size_t)(b*SEQL + l2)*DIN + h*HD + pg*4] = v;
        }
    }
}

// ---------------- K5: shift-combine + D-skip + gate + RMSNorm -> yn (bf16)
__global__ __launch_bounds__(256) void k_epi(const float* __restrict__ zx,
    const float* __restrict__ xBC, const float* __restrict__ yfw,
    const float* __restrict__ ybw, const float* __restrict__ fcD_w,
    const float* __restrict__ Dv, const float* __restrict__ norm_w,
    __hip_bfloat16* __restrict__ ynbf)
{
    const int m = blockIdx.x;
    const int l = m & (SEQL-1);
    const int d = threadIdx.x;
    const int lane = d & 63, wave = d >> 6;
    __shared__ float red[4][4];
    __shared__ float redq[4];
    float xs = xBC[(size_t)m*CONV_DIM + d];
    float yv = 0.f;
    if (l > 0)       yv += yfw[(size_t)(m-1)*DIN + d];
    if (l < SEQL-1)  yv += ybw[(size_t)(m+1)*DIN + d];
    float p0 = wave_sum(xs * fcD_w[0*DIN + d]);
    float p1 = wave_sum(xs * fcD_w[1*DIN + d]);
    float p2 = wave_sum(xs * fcD_w[2*DIN + d]);
    float p3 = wave_sum(xs * fcD_w[3*DIN + d]);
    if (lane == 0) { red[wave][0]=p0; red[wave][1]=p1; red[wave][2]=p2; red[wave][3]=p3; }
    __syncthreads();
    const int h = d >> 6;
    float scal = red[0][h] + red[1][h] + red[2][h] + red[3][h] + Dv[h];
    yv = fmaf(xs, scal, yv);
    float z  = zx[(size_t)m*DPROJ + d];
    float yz = yv * siluf(z);
    float q = wave_sum(yz*yz);
    if (lane == 0) redq[wave] = q;
    __syncthreads();
    float ms = (redq[0] + redq[1] + redq[2] + redq[3]) * (1.f/DIN);
    float r = rsqrtf(ms + 1e-5f);
    ynbf[(size_t)m*DIN + d] = __float2bfloat16(yz * r * norm_w[d]);
}

extern "C" void kernel_launch(void* const* d_in, const int* in_sizes, int n_in,
                              void* d_out, int out_size, void* d_ws, size_t ws_size,
                              hipStream_t stream)
{
    const float* x       = (const float*)d_in[0];
    const float* w_down  = (const float*)d_in[1];
    const float* b_down  = (const float*)d_in[2];
    const float* w_up    = (const float*)d_in[3];
    const float* b_up    = (const float*)d_in[4];
    const float* gate1   = (const float*)d_in[5];
    const float* in_w    = (const float*)d_in[6];
    const float* conv_w  = (const float*)d_in[7];
    const float* conv_b  = (const float*)d_in[8];
    const float* dt_bias = (const float*)d_in[9];
    const float* A_log   = (const float*)d_in[10];
    const float* Dv      = (const float*)d_in[11];
    const float* fcD_w   = (const float*)d_in[12];
    const float* norm_w  = (const float*)d_in[13];
    const float* out_w   = (const float*)d_in[14];
    float* out = (float*)d_out;
    float* ws  = (float*)d_ws;

    size_t off = 0;
    float* xmid = ws + off; off += (size_t)MROWS*DM;
    float* zx   = ws + off; off += (size_t)MROWS*DPROJ;
    float* xBC  = ws + off; off += (size_t)MROWS*CONV_DIM;
    float* yfw  = ws + off; off += (size_t)MROWS*DIN;
    float* ybw  = ws + off; off += (size_t)MROWS*DIN;
    float* Sbuf = ws + off; off += (size_t)1024*1024;
    float* Pbuf = ws + off; off += 1024;
    float* Hbuf = ws + off; off += (size_t)1024*1024;
    __hip_bfloat16* bfb = (__hip_bfloat16*)(ws + off);
    size_t bo = 0;
    __hip_bfloat16* wd_bf = bfb + bo; bo += 524288;
    __hip_bfloat16* wu_bf = bfb + bo; bo += 524288;
    __hip_bfloat16* wi_bf = bfb + bo; bo += 71680;
    __hip_bfloat16* wo_bf = bfb + bo; bo += 32768;
    __hip_bfloat16* u_bf  = bfb + bo; bo += (size_t)MROWS*DM;
    __hip_bfloat16* yn_bf = bfb + bo; bo += (size_t)MROWS*DIN;
    __hip_bfloat16* hc_bf = bfb + bo; bo += (size_t)MROWS*DM;
    float* partial = zx;   // alias: consumed before zx written

    k_prep_w<<<4504, 256, 0, stream>>>(w_down, w_up, in_w, out_w, wd_bf, wu_bf, wi_bf, wo_bf);

    dim3 gdown(MROWS/64, 2);
    k_down_mfma<<<gdown, 256, 0, stream>>>(x, wd_bf, partial);
    k_down_fix<<<MROWS*DM/1024, 256, 0, stream>>>(partial, b_down, xmid, u_bf);

    for (int pass = 0; pass < 2; ++pass) {
        dim3 gin(MROWS/64, 7);
        k_proj_in<<<gin, 256, 0, stream>>>(u_bf, wi_bf, zx);
        k_conv<<<(MROWS*CONV_DIM)/256, 256, 0, stream>>>(zx, conv_w, conv_b, xBC);
        {
            void* args[] = { (void*)&zx, (void*)&xBC, (void*)&dt_bias, (void*)&A_log,
                             (void*)&Sbuf, (void*)&Pbuf, (void*)&Hbuf,
                             (void*)&yfw, (void*)&ybw };
            hipLaunchCooperativeKernel((void*)k_scan_fused, dim3(1024), dim3(64),
                                       args, 0, stream);
        }
        k_epi<<<MROWS, 256, 0, stream>>>(zx, xBC, yfw, ybw, fcD_w, Dv, norm_w, yn_bf);
        if (pass == 0)
            k_proj_out_t<0><<<MROWS/64, 256, 0, stream>>>(yn_bf, wo_bf, xmid, gate1, u_bf, hc_bf);
        else
            k_proj_out_t<1><<<MROWS/64, 256, 0, stream>>>(yn_bf, wo_bf, xmid, gate1, u_bf, hc_bf);
    }

    dim3 gup(MROWS/64, HID/128);
    k_up_mfma<<<gup, 256, 0, stream>>>(hc_bf, wu_bf, b_up, x, out);
}

// Round 2
// 506.580 us; speedup vs baseline: 1.7865x; 1.7865x over previous
//
#include <hip/hip_runtime.h>
#include <hip/hip_bf16.h>
#include <math.h>

#define SEQL 2048
#define NB   4
#define HID  4096
#define DM   128
#define DIN  256
#define DST  16
#define HD   64
#define NH   4
#define CONV_DIM 288
#define DPROJ 552
#define MROWS (SEQL*NB)      // 8192
#define TCH 64
#define NCHUNK (SEQL/TCH)    // 32

typedef __attribute__((ext_vector_type(8))) short short8;
typedef __attribute__((ext_vector_type(4))) float f32x4;

__device__ __forceinline__ float siluf(float v){ return v / (1.f + expf(-v)); }
__device__ __forceinline__ float geluf(float v){ return 0.5f*v*(1.f + erff(v*0.70710678118654752f)); }
__device__ __forceinline__ float wave_sum(float v){
    #pragma unroll
    for (int o = 32; o > 0; o >>= 1) v += __shfl_xor(v, o, 64);
    return v;
}
__device__ __forceinline__ unsigned bfpack2(float a, float b){
    __hip_bfloat162 v = __float22bfloat162_rn(make_float2(a, b));
    return *reinterpret_cast<unsigned*>(&v);
}

// ---------------- prep: convert weights to bf16 (in_w padded 552->560 rows)
__global__ __launch_bounds__(256) void k_prep_w(const float* __restrict__ w_down,
    const float* __restrict__ w_up, const float* __restrict__ in_w,
    const float* __restrict__ out_w,
    __hip_bfloat16* __restrict__ wd, __hip_bfloat16* __restrict__ wu,
    __hip_bfloat16* __restrict__ wi, __hip_bfloat16* __restrict__ wo)
{
    int idx = blockIdx.x*256 + threadIdx.x;
    if (idx < 524288) { wd[idx] = __float2bfloat16(w_down[idx]); return; }
    idx -= 524288;
    if (idx < 524288) { wu[idx] = __float2bfloat16(w_up[idx]); return; }
    idx -= 524288;
    if (idx < 71680) { wi[idx] = (idx < 552*128) ? __float2bfloat16(in_w[idx]) : __float2bfloat16(0.f); return; }
    idx -= 71680;
    if (idx < 32768) { wo[idx] = __float2bfloat16(out_w[idx]); }
}

// ---------------- K1: down-proj MFMA, split-K x2, partial out
__global__ __launch_bounds__(256) void k_down_mfma(const float* __restrict__ x,
    const __hip_bfloat16* __restrict__ wbf, float* __restrict__ partial)
{
    __shared__ __align__(16) short Abuf[64][72];
    __shared__ __align__(16) short Wbuf[128][72];
    const int tid = threadIdx.x;
    const int m0 = blockIdx.x * 64;
    const int ks = blockIdx.y;
    const int b  = m0 >> 11, l0 = m0 & 2047;
    const int lane = tid & 63, wv = tid >> 6;
    const int fr = lane & 15, q = lane >> 4;
    f32x4 acc[8];
    #pragma unroll
    for (int i = 0; i < 8; ++i) acc[i] = (f32x4){0.f,0.f,0.f,0.f};

    const int arow = tid >> 2, aseg = tid & 3;   // A: 4 thr/row, 16 floats
    const int wrow = tid >> 1, wseg = tid & 1;   // W: 2 thr/row, 32 shorts

    for (int k0 = ks*2048; k0 < ks*2048 + 2048; k0 += 64) {
        const float4* ap = (const float4*)(x + (size_t)((l0 + arow)*NB + b)*HID + k0 + aseg*16);
        float4 f0 = ap[0], f1 = ap[1], f2 = ap[2], f3 = ap[3];
        const uint4* wp = (const uint4*)(wbf + (size_t)wrow*HID + k0 + wseg*32);
        uint4 w0 = wp[0], w1 = wp[1], w2 = wp[2], w3 = wp[3];
        uint4 pk0, pk1;
        pk0.x = bfpack2(f0.x,f0.y); pk0.y = bfpack2(f0.z,f0.w);
        pk0.z = bfpack2(f1.x,f1.y); pk0.w = bfpack2(f1.z,f1.w);
        pk1.x = bfpack2(f2.x,f2.y); pk1.y = bfpack2(f2.z,f2.w);
        pk1.z = bfpack2(f3.x,f3.y); pk1.w = bfpack2(f3.z,f3.w);
        uint4* adst = (uint4*)&Abuf[arow][aseg*16];
        adst[0] = pk0; adst[1] = pk1;
        uint4* wdst = (uint4*)&Wbuf[wrow][wseg*32];
        wdst[0] = w0; wdst[1] = w1; wdst[2] = w2; wdst[3] = w3;
        __syncthreads();
        #pragma unroll
        for (int kh = 0; kh < 2; ++kh) {
            short8 af = *reinterpret_cast<const short8*>(&Abuf[wv*16 + fr][kh*32 + q*8]);
            #pragma unroll
            for (int ns = 0; ns < 8; ++ns) {
                short8 bf = *reinterpret_cast<const short8*>(&Wbuf[ns*16 + fr][kh*32 + q*8]);
                acc[ns] = __builtin_amdgcn_mfma_f32_16x16x32_bf16(af, bf, acc[ns], 0, 0, 0);
            }
        }
        __syncthreads();
    }
    #pragma unroll
    for (int ns = 0; ns < 8; ++ns)
        #pragma unroll
        for (int r = 0; r < 4; ++r)
            partial[((size_t)ks*MROWS + m0 + wv*16 + q*4 + r)*DM + ns*16 + fr] = acc[ns][r];
}

// ---------------- K1b: partial reduce + bias + GELU -> xmid fp32 + u_bf
__global__ __launch_bounds__(256) void k_down_fix(const float* __restrict__ partial,
    const float* __restrict__ bias, float* __restrict__ xmid,
    __hip_bfloat16* __restrict__ ubf)
{
    size_t i4 = ((size_t)blockIdx.x*256 + threadIdx.x)*4;
    int n = (int)(i4 & (DM-1));
    float4 p0 = *(const float4*)&partial[i4];
    float4 p1 = *(const float4*)&partial[(size_t)MROWS*DM + i4];
    float4 bv = *(const float4*)&bias[n];
    float4 v;
    v.x = geluf(p0.x + p1.x + bv.x);
    v.y = geluf(p0.y + p1.y + bv.y);
    v.z = geluf(p0.z + p1.z + bv.z);
    v.w = geluf(p0.w + p1.w + bv.w);
    *(float4*)&xmid[i4] = v;
    uint2 pk; pk.x = bfpack2(v.x, v.y); pk.y = bfpack2(v.z, v.w);
    *(uint2*)&ubf[i4] = pk;
}

// ---------------- in-proj MFMA: zx = u(bf16) @ in_w(bf16)^T  (N padded to 560)
__global__ __launch_bounds__(256) void k_proj_in(const __hip_bfloat16* __restrict__ ubf,
    const __hip_bfloat16* __restrict__ wbf, float* __restrict__ zx)
{
    __shared__ __align__(16) short Abuf[64][136];
    __shared__ __align__(16) short Wbuf[80][136];
    const int tid = threadIdx.x;
    const int m0 = blockIdx.x*64;
    const int n0 = blockIdx.y*80;
    for (int i = tid; i < 64*16; i += 256) {
        int r = i >> 4, s = i & 15;
        *(uint4*)&Abuf[r][s*8] = *(const uint4*)&ubf[(size_t)(m0+r)*DM + s*8];
    }
    for (int i = tid; i < 80*16; i += 256) {
        int r = i >> 4, s = i & 15;
        *(uint4*)&Wbuf[r][s*8] = *(const uint4*)&wbf[(size_t)(n0+r)*DM + s*8];
    }
    __syncthreads();
    const int lane = tid & 63, wv = tid >> 6, fr = lane & 15, q = lane >> 4;
    f32x4 acc[5];
    #pragma unroll
    for (int i = 0; i < 5; ++i) acc[i] = (f32x4){0.f,0.f,0.f,0.f};
    #pragma unroll
    for (int kt = 0; kt < 4; ++kt) {
        short8 af = *reinterpret_cast<const short8*>(&Abuf[wv*16 + fr][kt*32 + q*8]);
        #pragma unroll
        for (int ns = 0; ns < 5; ++ns) {
            short8 bf = *reinterpret_cast<const short8*>(&Wbuf[ns*16 + fr][kt*32 + q*8]);
            acc[ns] = __builtin_amdgcn_mfma_f32_16x16x32_bf16(af, bf, acc[ns], 0, 0, 0);
        }
    }
    #pragma unroll
    for (int ns = 0; ns < 5; ++ns) {
        int n = n0 + ns*16 + fr;
        if (n < DPROJ) {
            #pragma unroll
            for (int r = 0; r < 4; ++r)
                zx[(size_t)(m0 + wv*16 + q*4 + r)*DPROJ + n] = acc[ns][r];
        }
    }
}

// ---------------- out-proj MFMA, pass-templated epilogue:
// PASS 0: write u_bf only (h never consumed)
// PASS 1: fuse xmid blend -> hc_bf directly (replaces k_prep_up + h2 roundtrip)
template<int PASS>
__global__ __launch_bounds__(256) void k_proj_out_t(const __hip_bfloat16* __restrict__ ynbf,
    const __hip_bfloat16* __restrict__ wbf, const float* __restrict__ xmid,
    const float* __restrict__ gate1,
    __hip_bfloat16* __restrict__ ubf, __hip_bfloat16* __restrict__ hcbf)
{
    __shared__ __align__(16) short Abuf[64][136];
    __shared__ __align__(16) short Wbuf[128][136];
    const int tid = threadIdx.x;
    const int m0 = blockIdx.x*64;
    const int lane = tid & 63, wv = tid >> 6, fr = lane & 15, q = lane >> 4;
    f32x4 acc[8];
    #pragma unroll
    for (int i = 0; i < 8; ++i) acc[i] = (f32x4){0.f,0.f,0.f,0.f};
    for (int kb = 0; kb < 2; ++kb) {
        if (kb) __syncthreads();
        for (int i = tid; i < 64*16; i += 256) {
            int r = i >> 4, s = i & 15;
            *(uint4*)&Abuf[r][s*8] = *(const uint4*)&ynbf[(size_t)(m0+r)*DIN + kb*128 + s*8];
        }
        for (int i = tid; i < 128*16; i += 256) {
            int r = i >> 4, s = i & 15;
            *(uint4*)&Wbuf[r][s*8] = *(const uint4*)&wbf[(size_t)r*DIN + kb*128 + s*8];
        }
        __syncthreads();
        #pragma unroll
        for (int kt = 0; kt < 4; ++kt) {
            short8 af = *reinterpret_cast<const short8*>(&Abuf[wv*16 + fr][kt*32 + q*8]);
            #pragma unroll
            for (int ns = 0; ns < 8; ++ns) {
                short8 bf = *reinterpret_cast<const short8*>(&Wbuf[ns*16 + fr][kt*32 + q*8]);
                acc[ns] = __builtin_amdgcn_mfma_f32_16x16x32_bf16(af, bf, acc[ns], 0, 0, 0);
            }
        }
    }
    float ca = 0.f, cb = 0.f;
    if (PASS == 1) {
        float al = 1.f / (1.f + expf(-gate1[0]));
        ca = 1.f + al; cb = 1.f - al;
    }
    #pragma unroll
    for (int ns = 0; ns < 8; ++ns)
        #pragma unroll
        for (int r = 0; r < 4; ++r) {
            int m = m0 + wv*16 + q*4 + r, n = ns*16 + fr;
            float v = acc[ns][r];
            if (PASS == 0) {
                ubf[(size_t)m*DM + n] = __float2bfloat16(v);
            } else {
                float xm = xmid[(size_t)m*DM + n];
                hcbf[(size_t)m*DM + n] = __float2bfloat16(ca*xm + cb*v);
            }
        }
}

// ---------------- up-proj MFMA + bias + residual + transpose store
__global__ __launch_bounds__(256) void k_up_mfma(const __hip_bfloat16* __restrict__ hc,
    const __hip_bfloat16* __restrict__ wbf, const float* __restrict__ b_up,
    const float* __restrict__ x, float* __restrict__ out)
{
    __shared__ __align__(16) short Abuf[64][136];
    __shared__ __align__(16) short Wbuf[128][136];
    const int tid = threadIdx.x;
    const int m0 = blockIdx.x*64;
    const int n0 = blockIdx.y*128;
    for (int i = tid; i < 64*16; i += 256) {
        int r = i >> 4, s = i & 15;
        *(uint4*)&Abuf[r][s*8] = *(const uint4*)&hc[(size_t)(m0+r)*DM + s*8];
    }
    for (int i = tid; i < 128*16; i += 256) {
        int r = i >> 4, s = i & 15;
        *(uint4*)&Wbuf[r][s*8] = *(const uint4*)&wbf[(size_t)(n0+r)*DM + s*8];
    }
    __syncthreads();
    const int lane = tid & 63, wv = tid >> 6, fr = lane & 15, q = lane >> 4;
    f32x4 acc[8];
    #pragma unroll
    for (int i = 0; i < 8; ++i) acc[i] = (f32x4){0.f,0.f,0.f,0.f};
    #pragma unroll
    for (int kt = 0; kt < 4; ++kt) {
        short8 af = *reinterpret_cast<const short8*>(&Abuf[wv*16 + fr][kt*32 + q*8]);
        #pragma unroll
        for (int ns = 0; ns < 8; ++ns) {
            short8 bf = *reinterpret_cast<const short8*>(&Wbuf[ns*16 + fr][kt*32 + q*8]);
            acc[ns] = __builtin_amdgcn_mfma_f32_16x16x32_bf16(af, bf, acc[ns], 0, 0, 0);
        }
    }
    #pragma unroll
    for (int r = 0; r < 4; ++r) {
        int m = m0 + wv*16 + q*4 + r;
        int b = m >> 11, l = m & 2047;
        size_t rowbase = (size_t)(l*NB + b)*HID + n0;
        #pragma unroll
        for (int ns = 0; ns < 8; ++ns) {
            int n = ns*16 + fr;
            out[rowbase + n] = acc[ns][r] + b_up[n0 + n] + x[rowbase + n];
        }
    }
}

// ---------------- K3: causal depthwise conv7 + bias + silu
__global__ __launch_bounds__(256) void k_conv(const float* __restrict__ zx,
    const float* __restrict__ cw, const float* __restrict__ cb,
    float* __restrict__ xBC)
{
    int idx = blockIdx.x*256 + threadIdx.x;
    if (idx >= MROWS*CONV_DIM) return;
    int c = idx % CONV_DIM;
    int m = idx / CONV_DIM;
    int l = m & 2047, b = m >> 11;
    float acc = cb[c];
    #pragma unroll
    for (int k = 0; k < 7; ++k) {
        int l2 = l - 6 + k;
        if (l2 >= 0)
            acc = fmaf(zx[(size_t)(b*SEQL + l2)*DPROJ + DIN + c], cw[c*7 + k], acc);
    }
    xBC[(size_t)m*CONV_DIM + c] = siluf(acc);
}

// ---------------- K4a: chunk-local scan states (coalesced float4 staging,
//                  wave-parallel decay product)
__global__ __launch_bounds__(64) void k_scan_state(const float* __restrict__ zx,
    const float* __restrict__ xBC, const float* __restrict__ dt_bias,
    const float* __restrict__ A_log, float* __restrict__ Sbuf, float* __restrict__ Pbuf)
{
    const int bid = blockIdx.x;
    const int c   = bid & (NCHUNK-1);
    const int h   = (bid >> 5) & (NH-1);
    const int b   = (bid >> 7) & 3;
    const int dir = bid >> 9;
    const int tid = threadIdx.x;
    __shared__ float dA_s[TCH], dt_s[TCH];
    __shared__ float Xs[TCH][HD];
    __shared__ float Bs[TCH][DST];
    {
        const int kk = tid;
        const int l = dir ? (SEQL-1 - (c*TCH + kk)) : (c*TCH + kk);
        float dtraw = zx[(size_t)(b*SEQL + l)*DPROJ + 544 + dir*NH + h] + dt_bias[h];
        float dt = dtraw > 20.f ? dtraw : log1pf(expf(dtraw));
        dt_s[kk] = dt;
        dA_s[kk] = expf(dt * (-expf(A_log[h])));
    }
    __syncthreads();
    #pragma unroll
    for (int t = 0; t < 16; ++t) {
        int k2 = t*4 + (tid >> 4);
        int p4 = (tid & 15)*4;
        int l2 = dir ? (SEQL-1 - (c*TCH + k2)) : (c*TCH + k2);
        float4 v = *(const float4*)&xBC[(size_t)(b*SEQL + l2)*CONV_DIM + h*HD + p4];
        float sc = dt_s[k2];
        v.x *= sc; v.y *= sc; v.z *= sc; v.w *= sc;
        *(float4*)&Xs[k2][p4] = v;
    }
    #pragma unroll
    for (int t = 0; t < 4; ++t) {
        int k2 = t*16 + (tid >> 2);
        int n4 = (tid & 3)*4;
        int l2 = dir ? (SEQL-1 - (c*TCH + k2)) : (c*TCH + k2);
        *(float4*)&Bs[k2][n4] = *(const float4*)&xBC[(size_t)(b*SEQL + l2)*CONV_DIM + DIN + n4];
    }
    __syncthreads();
    const int pg = tid >> 2, ng = tid & 3;
    float s[4][4];
    #pragma unroll
    for (int i = 0; i < 4; ++i)
        #pragma unroll
        for (int j = 0; j < 4; ++j) s[i][j] = 0.f;
    for (int k2 = 0; k2 < TCH; ++k2) {
        float dAv = dA_s[k2];
        float4 xv = *(const float4*)&Xs[k2][pg*4];
        float4 bv = *(const float4*)&Bs[k2][ng*4];
        float xa[4] = {xv.x, xv.y, xv.z, xv.w};
        float ba[4] = {bv.x, bv.y, bv.z, bv.w};
        #pragma unroll
        for (int i = 0; i < 4; ++i)
            #pragma unroll
            for (int j = 0; j < 4; ++j)
                s[i][j] = fmaf(dAv, s[i][j], xa[i]*ba[j]);
    }
    size_t sb = (size_t)bid * 1024;
    #pragma unroll
    for (int i = 0; i < 4; ++i) {
        float4 v = {s[i][0], s[i][1], s[i][2], s[i][3]};
        *(float4*)&Sbuf[sb + (size_t)((pg*4+i)*16 + ng*4)] = v;
    }
    {   // wave-parallel product of 64 decays (was serial on lane 0)
        float pv = dA_s[tid];
        #pragma unroll
        for (int o = 32; o > 0; o >>= 1) pv *= __shfl_xor(pv, o, 64);
        if (tid == 0) Pbuf[bid] = pv;
    }
}

// ---------------- K4b: register-pipelined combine. 32768 independent chains,
// one per thread, 512 blocks (was 32 blocks with a serial global chain).
__global__ __launch_bounds__(64) void k_scan_combine2(const float* __restrict__ Sbuf,
    const float* __restrict__ Pbuf, float* __restrict__ Hbuf)
{
    const int gt = blockIdx.x*64 + threadIdx.x;
    const int g = gt >> 10, e = gt & 1023;
    float sv[NCHUNK], pw[NCHUNK];
    #pragma unroll
    for (int cc = 0; cc < NCHUNK; ++cc)
        sv[cc] = Sbuf[(size_t)(g*NCHUNK + cc)*1024 + e];
    #pragma unroll
    for (int cc = 0; cc < NCHUNK; ++cc)
        pw[cc] = Pbuf[g*NCHUNK + cc];
    float carry = 0.f;
    #pragma unroll
    for (int cc = 0; cc < NCHUNK; ++cc) {
        Hbuf[(size_t)(g*NCHUNK + cc)*1024 + e] = carry;
        carry = fmaf(pw[cc], carry, sv[cc]);
    }
}

// ---------------- K4c: replay with correct init, emit y
__global__ __launch_bounds__(64) void k_scan_out(const float* __restrict__ zx,
    const float* __restrict__ xBC, const float* __restrict__ dt_bias,
    const float* __restrict__ A_log, const float* __restrict__ Hbuf,
    float* __restrict__ yfw, float* __restrict__ ybw)
{
    const int bid = blockIdx.x;
    const int c   = bid & (NCHUNK-1);
    const int h   = (bid >> 5) & (NH-1);
    const int b   = (bid >> 7) & 3;
    const int dir = bid >> 9;
    const int tid = threadIdx.x;
    __shared__ float dA_s[TCH], dt_s[TCH];
    __shared__ float Xs[TCH][HD];
    __shared__ float Bs[TCH][DST];
    __shared__ float Cs[TCH][DST];
    {
        const int kk = tid;
        const int l = dir ? (SEQL-1 - (c*TCH + kk)) : (c*TCH + kk);
        float dtraw = zx[(size_t)(b*SEQL + l)*DPROJ + 544 + dir*NH + h] + dt_bias[h];
        float dt = dtraw > 20.f ? dtraw : log1pf(expf(dtraw));
        dt_s[kk] = dt;
        dA_s[kk] = expf(dt * (-expf(A_log[h])));
    }
    __syncthreads();
    #pragma unroll
    for (int t = 0; t < 16; ++t) {
        int k2 = t*4 + (tid >> 4);
        int p4 = (tid & 15)*4;
        int l2 = dir ? (SEQL-1 - (c*TCH + k2)) : (c*TCH + k2);
        float4 v = *(const float4*)&xBC[(size_t)(b*SEQL + l2)*CONV_DIM + h*HD + p4];
        float sc = dt_s[k2];
        v.x *= sc; v.y *= sc; v.z *= sc; v.w *= sc;
        *(float4*)&Xs[k2][p4] = v;
    }
    #pragma unroll
    for (int t = 0; t < 4; ++t) {
        int k2 = t*16 + (tid >> 2);
        int n4 = (tid & 3)*4;
        int l2 = dir ? (SEQL-1 - (c*TCH + k2)) : (c*TCH + k2);
        *(float4*)&Bs[k2][n4] = *(const float4*)&xBC[(size_t)(b*SEQL + l2)*CONV_DIM + DIN + n4];
        *(float4*)&Cs[k2][n4] = *(const float4*)&xBC[(size_t)(b*SEQL + l2)*CONV_DIM + DIN + DST + n4];
    }
    __syncthreads();
    const int pg = tid >> 2, ng = tid & 3;
    float s[4][4];
    size_t hb = (size_t)bid * 1024;
    #pragma unroll
    for (int i = 0; i < 4; ++i) {
        float4 v = *(const float4*)&Hbuf[hb + (size_t)((pg*4+i)*16 + ng*4)];
        s[i][0] = v.x; s[i][1] = v.y; s[i][2] = v.z; s[i][3] = v.w;
    }
    float* yout = dir ? ybw : yfw;
    for (int k2 = 0; k2 < TCH; ++k2) {
        float dAv = dA_s[k2];
        float4 xv = *(const float4*)&Xs[k2][pg*4];
        float4 bv = *(const float4*)&Bs[k2][ng*4];
        float4 cv = *(const float4*)&Cs[k2][ng*4];
        float xa[4] = {xv.x, xv.y, xv.z, xv.w};
        float ba[4] = {bv.x, bv.y, bv.z, bv.w};
        float ca[4] = {cv.x, cv.y, cv.z, cv.w};
        float y[4];
        #pragma unroll
        for (int i = 0; i < 4; ++i) {
            #pragma unroll
            for (int j = 0; j < 4; ++j)
                s[i][j] = fmaf(dAv, s[i][j], xa[i]*ba[j]);
            y[i] = s[i][0]*ca[0] + s[i][1]*ca[1] + s[i][2]*ca[2] + s[i][3]*ca[3];
        }
        #pragma unroll
        for (int i = 0; i < 4; ++i) {
            y[i] += __shfl_xor(y[i], 1, 64);
            y[i] += __shfl_xor(y[i], 2, 64);
        }
        if (ng == 0) {
            int l2 = dir ? (SEQL-1 - (c*TCH + k2)) : (c*TCH + k2);
            float4 v = {y[0], y[1], y[2], y[3]};
            *(float4*)&yout[(size_t)(b*SEQL + l2)*DIN + h*HD + pg*4] = v;
        }
    }
}

// ---------------- K5: shift-combine + D-skip + gate + RMSNorm -> yn (bf16)
__global__ __launch_bounds__(256) void k_epi(const float* __restrict__ zx,
    const float* __restrict__ xBC, const float* __restrict__ yfw,
    const float* __restrict__ ybw, const float* __restrict__ fcD_w,
    const float* __restrict__ Dv, const float* __restrict__ norm_w,
    __hip_bfloat16* __restrict__ ynbf)
{
    const int m = blockIdx.x;
    const int l = m & (SEQL-1);
    const int d = threadIdx.x;
    const int lane = d & 63, wave = d >> 6;
    __shared__ float red[4][4];
    __shared__ float redq[4];
    float xs = xBC[(size_t)m*CONV_DIM + d];
    float yv = 0.f;
    if (l > 0)       yv += yfw[(size_t)(m-1)*DIN + d];
    if (l < SEQL-1)  yv += ybw[(size_t)(m+1)*DIN + d];
    float p0 = wave_sum(xs * fcD_w[0*DIN + d]);
    float p1 = wave_sum(xs * fcD_w[1*DIN + d]);
    float p2 = wave_sum(xs * fcD_w[2*DIN + d]);
    float p3 = wave_sum(xs * fcD_w[3*DIN + d]);
    if (lane == 0) { red[wave][0]=p0; red[wave][1]=p1; red[wave][2]=p2; red[wave][3]=p3; }
    __syncthreads();
    const int h = d >> 6;
    float scal = red[0][h] + red[1][h] + red[2][h] + red[3][h] + Dv[h];
    yv = fmaf(xs, scal, yv);
    float z  = zx[(size_t)m*DPROJ + d];
    float yz = yv * siluf(z);
    float q = wave_sum(yz*yz);
    if (lane == 0) redq[wave] = q;
    __syncthreads();
    float ms = (redq[0] + redq[1] + redq[2] + redq[3]) * (1.f/DIN);
    float r = rsqrtf(ms + 1e-5f);
    ynbf[(size_t)m*DIN + d] = __float2bfloat16(yz * r * norm_w[d]);
}

extern "C" void kernel_launch(void* const* d_in, const int* in_sizes, int n_in,
                              void* d_out, int out_size, void* d_ws, size_t ws_size,
                              hipStream_t stream)
{
    const float* x       = (const float*)d_in[0];
    const float* w_down  = (const float*)d_in[1];
    const float* b_down  = (const float*)d_in[2];
    const float* w_up    = (const float*)d_in[3];
    const float* b_up    = (const float*)d_in[4];
    const float* gate1   = (const float*)d_in[5];
    const float* in_w    = (const float*)d_in[6];
    const float* conv_w  = (const float*)d_in[7];
    const float* conv_b  = (const float*)d_in[8];
    const float* dt_bias = (const float*)d_in[9];
    const float* A_log   = (const float*)d_in[10];
    const float* Dv      = (const float*)d_in[11];
    const float* fcD_w   = (const float*)d_in[12];
    const float* norm_w  = (const float*)d_in[13];
    const float* out_w   = (const float*)d_in[14];
    float* out = (float*)d_out;
    float* ws  = (float*)d_ws;

    size_t off = 0;
    float* xmid = ws + off; off += (size_t)MROWS*DM;
    float* zx   = ws + off; off += (size_t)MROWS*DPROJ;
    float* xBC  = ws + off; off += (size_t)MROWS*CONV_DIM;
    float* yfw  = ws + off; off += (size_t)MROWS*DIN;
    float* ybw  = ws + off; off += (size_t)MROWS*DIN;
    float* Sbuf = ws + off; off += (size_t)1024*1024;
    float* Pbuf = ws + off; off += 1024;
    float* Hbuf = ws + off; off += (size_t)1024*1024;
    __hip_bfloat16* bfb = (__hip_bfloat16*)(ws + off);
    size_t bo = 0;
    __hip_bfloat16* wd_bf = bfb + bo; bo += 524288;
    __hip_bfloat16* wu_bf = bfb + bo; bo += 524288;
    __hip_bfloat16* wi_bf = bfb + bo; bo += 71680;
    __hip_bfloat16* wo_bf = bfb + bo; bo += 32768;
    __hip_bfloat16* u_bf  = bfb + bo; bo += (size_t)MROWS*DM;
    __hip_bfloat16* yn_bf = bfb + bo; bo += (size_t)MROWS*DIN;
    __hip_bfloat16* hc_bf = bfb + bo; bo += (size_t)MROWS*DM;
    float* partial = zx;   // alias: consumed before zx written

    k_prep_w<<<4504, 256, 0, stream>>>(w_down, w_up, in_w, out_w, wd_bf, wu_bf, wi_bf, wo_bf);

    dim3 gdown(MROWS/64, 2);
    k_down_mfma<<<gdown, 256, 0, stream>>>(x, wd_bf, partial);
    k_down_fix<<<MROWS*DM/1024, 256, 0, stream>>>(partial, b_down, xmid, u_bf);

    for (int pass = 0; pass < 2; ++pass) {
        dim3 gin(MROWS/64, 7);
        k_proj_in<<<gin, 256, 0, stream>>>(u_bf, wi_bf, zx);
        k_conv<<<(MROWS*CONV_DIM)/256, 256, 0, stream>>>(zx, conv_w, conv_b, xBC);
        k_scan_state<<<1024, 64, 0, stream>>>(zx, xBC, dt_bias, A_log, Sbuf, Pbuf);
        k_scan_combine2<<<512, 64, 0, stream>>>(Sbuf, Pbuf, Hbuf);
        k_scan_out<<<1024, 64, 0, stream>>>(zx, xBC, dt_bias, A_log, Hbuf, yfw, ybw);
        k_epi<<<MROWS, 256, 0, stream>>>(zx, xBC, yfw, ybw, fcD_w, Dv, norm_w, yn_bf);
        if (pass == 0)
            k_proj_out_t<0><<<MROWS/64, 256, 0, stream>>>(yn_bf, wo_bf, xmid, gate1, u_bf, hc_bf);
        else
            k_proj_out_t<1><<<MROWS/64, 256, 0, stream>>>(yn_bf, wo_bf, xmid, gate1, u_bf, hc_bf);
    }

    dim3 gup(MROWS/64, HID/128);
    k_up_mfma<<<gup, 256, 0, stream>>>(hc_bf, wu_bf, b_up, x, out);
}

// Round 3
// 503.859 us; speedup vs baseline: 1.7961x; 1.0054x over previous
//
#include <hip/hip_runtime.h>
#include <hip/hip_bf16.h>
#include <math.h>

#define SEQL 2048
#define NB   4
#define HID  4096
#define DM   128
#define DIN  256
#define DST  16
#define HD   64
#define NH   4
#define CONV_DIM 288
#define DPROJ 552
#define MROWS (SEQL*NB)      // 8192
#define TCH 64
#define NCHUNK (SEQL/TCH)    // 32
#define KSPLIT 4

typedef __attribute__((ext_vector_type(8))) short short8;
typedef __attribute__((ext_vector_type(4))) float f32x4;

__device__ __forceinline__ float siluf(float v){ return v / (1.f + expf(-v)); }
__device__ __forceinline__ float geluf(float v){ return 0.5f*v*(1.f + erff(v*0.70710678118654752f)); }
__device__ __forceinline__ float wave_sum(float v){
    #pragma unroll
    for (int o = 32; o > 0; o >>= 1) v += __shfl_xor(v, o, 64);
    return v;
}
__device__ __forceinline__ unsigned bfpack2(float a, float b){
    __hip_bfloat162 v = __float22bfloat162_rn(make_float2(a, b));
    return *reinterpret_cast<unsigned*>(&v);
}

// ---------------- prep: convert weights to bf16 (in_w padded 552->560 rows)
__global__ __launch_bounds__(256) void k_prep_w(const float* __restrict__ w_down,
    const float* __restrict__ w_up, const float* __restrict__ in_w,
    const float* __restrict__ out_w,
    __hip_bfloat16* __restrict__ wd, __hip_bfloat16* __restrict__ wu,
    __hip_bfloat16* __restrict__ wi, __hip_bfloat16* __restrict__ wo)
{
    int idx = blockIdx.x*256 + threadIdx.x;
    if (idx < 524288) { wd[idx] = __float2bfloat16(w_down[idx]); return; }
    idx -= 524288;
    if (idx < 524288) { wu[idx] = __float2bfloat16(w_up[idx]); return; }
    idx -= 524288;
    if (idx < 71680) { wi[idx] = (idx < 552*128) ? __float2bfloat16(in_w[idx]) : __float2bfloat16(0.f); return; }
    idx -= 71680;
    if (idx < 32768) { wo[idx] = __float2bfloat16(out_w[idx]); }
}

// ---------------- K1: down-proj MFMA, split-K x4, partial out
__global__ __launch_bounds__(256) void k_down_mfma(const float* __restrict__ x,
    const __hip_bfloat16* __restrict__ wbf, float* __restrict__ partial)
{
    __shared__ __align__(16) short Abuf[64][72];
    __shared__ __align__(16) short Wbuf[128][72];
    const int tid = threadIdx.x;
    const int m0 = blockIdx.x * 64;
    const int ks = blockIdx.y;
    const int b  = m0 >> 11, l0 = m0 & 2047;
    const int lane = tid & 63, wv = tid >> 6;
    const int fr = lane & 15, q = lane >> 4;
    f32x4 acc[8];
    #pragma unroll
    for (int i = 0; i < 8; ++i) acc[i] = (f32x4){0.f,0.f,0.f,0.f};

    const int arow = tid >> 2, aseg = tid & 3;   // A: 4 thr/row, 16 floats
    const int wrow = tid >> 1, wseg = tid & 1;   // W: 2 thr/row, 32 shorts

    const int kbase = ks * (HID/KSPLIT);
    for (int k0 = kbase; k0 < kbase + HID/KSPLIT; k0 += 64) {
        const float4* ap = (const float4*)(x + (size_t)((l0 + arow)*NB + b)*HID + k0 + aseg*16);
        float4 f0 = ap[0], f1 = ap[1], f2 = ap[2], f3 = ap[3];
        const uint4* wp = (const uint4*)(wbf + (size_t)wrow*HID + k0 + wseg*32);
        uint4 w0 = wp[0], w1 = wp[1], w2 = wp[2], w3 = wp[3];
        uint4 pk0, pk1;
        pk0.x = bfpack2(f0.x,f0.y); pk0.y = bfpack2(f0.z,f0.w);
        pk0.z = bfpack2(f1.x,f1.y); pk0.w = bfpack2(f1.z,f1.w);
        pk1.x = bfpack2(f2.x,f2.y); pk1.y = bfpack2(f2.z,f2.w);
        pk1.z = bfpack2(f3.x,f3.y); pk1.w = bfpack2(f3.z,f3.w);
        uint4* adst = (uint4*)&Abuf[arow][aseg*16];
        adst[0] = pk0; adst[1] = pk1;
        uint4* wdst = (uint4*)&Wbuf[wrow][wseg*32];
        wdst[0] = w0; wdst[1] = w1; wdst[2] = w2; wdst[3] = w3;
        __syncthreads();
        #pragma unroll
        for (int kh = 0; kh < 2; ++kh) {
            short8 af = *reinterpret_cast<const short8*>(&Abuf[wv*16 + fr][kh*32 + q*8]);
            #pragma unroll
            for (int ns = 0; ns < 8; ++ns) {
                short8 bf = *reinterpret_cast<const short8*>(&Wbuf[ns*16 + fr][kh*32 + q*8]);
                acc[ns] = __builtin_amdgcn_mfma_f32_16x16x32_bf16(af, bf, acc[ns], 0, 0, 0);
            }
        }
        __syncthreads();
    }
    #pragma unroll
    for (int ns = 0; ns < 8; ++ns)
        #pragma unroll
        for (int r = 0; r < 4; ++r)
            partial[((size_t)ks*MROWS + m0 + wv*16 + q*4 + r)*DM + ns*16 + fr] = acc[ns][r];
}

// ---------------- K1b: partial reduce + bias + GELU -> xmid fp32 + u_bf
__global__ __launch_bounds__(256) void k_down_fix(const float* __restrict__ partial,
    const float* __restrict__ bias, float* __restrict__ xmid,
    __hip_bfloat16* __restrict__ ubf)
{
    size_t i4 = ((size_t)blockIdx.x*256 + threadIdx.x)*4;
    int n = (int)(i4 & (DM-1));
    float4 p0 = *(const float4*)&partial[i4];
    float4 p1 = *(const float4*)&partial[(size_t)MROWS*DM + i4];
    float4 p2 = *(const float4*)&partial[(size_t)2*MROWS*DM + i4];
    float4 p3 = *(const float4*)&partial[(size_t)3*MROWS*DM + i4];
    float4 bv = *(const float4*)&bias[n];
    float4 v;
    v.x = geluf(p0.x + p1.x + p2.x + p3.x + bv.x);
    v.y = geluf(p0.y + p1.y + p2.y + p3.y + bv.y);
    v.z = geluf(p0.z + p1.z + p2.z + p3.z + bv.z);
    v.w = geluf(p0.w + p1.w + p2.w + p3.w + bv.w);
    *(float4*)&xmid[i4] = v;
    uint2 pk; pk.x = bfpack2(v.x, v.y); pk.y = bfpack2(v.z, v.w);
    *(uint2*)&ubf[i4] = pk;
}

// ---------------- in-proj MFMA: zx = u(bf16) @ in_w(bf16)^T  (N padded to 560)
__global__ __launch_bounds__(256) void k_proj_in(const __hip_bfloat16* __restrict__ ubf,
    const __hip_bfloat16* __restrict__ wbf, float* __restrict__ zx)
{
    __shared__ __align__(16) short Abuf[64][136];
    __shared__ __align__(16) short Wbuf[80][136];
    const int tid = threadIdx.x;
    const int m0 = blockIdx.x*64;
    const int n0 = blockIdx.y*80;
    for (int i = tid; i < 64*16; i += 256) {
        int r = i >> 4, s = i & 15;
        *(uint4*)&Abuf[r][s*8] = *(const uint4*)&ubf[(size_t)(m0+r)*DM + s*8];
    }
    for (int i = tid; i < 80*16; i += 256) {
        int r = i >> 4, s = i & 15;
        *(uint4*)&Wbuf[r][s*8] = *(const uint4*)&wbf[(size_t)(n0+r)*DM + s*8];
    }
    __syncthreads();
    const int lane = tid & 63, wv = tid >> 6, fr = lane & 15, q = lane >> 4;
    f32x4 acc[5];
    #pragma unroll
    for (int i = 0; i < 5; ++i) acc[i] = (f32x4){0.f,0.f,0.f,0.f};
    #pragma unroll
    for (int kt = 0; kt < 4; ++kt) {
        short8 af = *reinterpret_cast<const short8*>(&Abuf[wv*16 + fr][kt*32 + q*8]);
        #pragma unroll
        for (int ns = 0; ns < 5; ++ns) {
            short8 bf = *reinterpret_cast<const short8*>(&Wbuf[ns*16 + fr][kt*32 + q*8]);
            acc[ns] = __builtin_amdgcn_mfma_f32_16x16x32_bf16(af, bf, acc[ns], 0, 0, 0);
        }
    }
    #pragma unroll
    for (int ns = 0; ns < 5; ++ns) {
        int n = n0 + ns*16 + fr;
        if (n < DPROJ) {
            #pragma unroll
            for (int r = 0; r < 4; ++r)
                zx[(size_t)(m0 + wv*16 + q*4 + r)*DPROJ + n] = acc[ns][r];
        }
    }
}

// ---------------- out-proj MFMA, pass-templated epilogue:
// PASS 0: write u_bf only; PASS 1: fuse xmid blend -> hc_bf directly
template<int PASS>
__global__ __launch_bounds__(256) void k_proj_out_t(const __hip_bfloat16* __restrict__ ynbf,
    const __hip_bfloat16* __restrict__ wbf, const float* __restrict__ xmid,
    const float* __restrict__ gate1,
    __hip_bfloat16* __restrict__ ubf, __hip_bfloat16* __restrict__ hcbf)
{
    __shared__ __align__(16) short Abuf[64][136];
    __shared__ __align__(16) short Wbuf[128][136];
    const int tid = threadIdx.x;
    const int m0 = blockIdx.x*64;
    const int lane = tid & 63, wv = tid >> 6, fr = lane & 15, q = lane >> 4;
    f32x4 acc[8];
    #pragma unroll
    for (int i = 0; i < 8; ++i) acc[i] = (f32x4){0.f,0.f,0.f,0.f};
    for (int kb = 0; kb < 2; ++kb) {
        if (kb) __syncthreads();
        for (int i = tid; i < 64*16; i += 256) {
            int r = i >> 4, s = i & 15;
            *(uint4*)&Abuf[r][s*8] = *(const uint4*)&ynbf[(size_t)(m0+r)*DIN + kb*128 + s*8];
        }
        for (int i = tid; i < 128*16; i += 256) {
            int r = i >> 4, s = i & 15;
            *(uint4*)&Wbuf[r][s*8] = *(const uint4*)&wbf[(size_t)r*DIN + kb*128 + s*8];
        }
        __syncthreads();
        #pragma unroll
        for (int kt = 0; kt < 4; ++kt) {
            short8 af = *reinterpret_cast<const short8*>(&Abuf[wv*16 + fr][kt*32 + q*8]);
            #pragma unroll
            for (int ns = 0; ns < 8; ++ns) {
                short8 bf = *reinterpret_cast<const short8*>(&Wbuf[ns*16 + fr][kt*32 + q*8]);
                acc[ns] = __builtin_amdgcn_mfma_f32_16x16x32_bf16(af, bf, acc[ns], 0, 0, 0);
            }
        }
    }
    float ca = 0.f, cb = 0.f;
    if (PASS == 1) {
        float al = 1.f / (1.f + expf(-gate1[0]));
        ca = 1.f + al; cb = 1.f - al;
    }
    #pragma unroll
    for (int ns = 0; ns < 8; ++ns)
        #pragma unroll
        for (int r = 0; r < 4; ++r) {
            int m = m0 + wv*16 + q*4 + r, n = ns*16 + fr;
            float v = acc[ns][r];
            if (PASS == 0) {
                ubf[(size_t)m*DM + n] = __float2bfloat16(v);
            } else {
                float xm = xmid[(size_t)m*DM + n];
                hcbf[(size_t)m*DM + n] = __float2bfloat16(ca*xm + cb*v);
            }
        }
}

// ---------------- up-proj MFMA + bias + residual + transpose store
__global__ __launch_bounds__(256) void k_up_mfma(const __hip_bfloat16* __restrict__ hc,
    const __hip_bfloat16* __restrict__ wbf, const float* __restrict__ b_up,
    const float* __restrict__ x, float* __restrict__ out)
{
    __shared__ __align__(16) short Abuf[64][136];
    __shared__ __align__(16) short Wbuf[128][136];
    const int tid = threadIdx.x;
    const int m0 = blockIdx.x*64;
    const int n0 = blockIdx.y*128;
    for (int i = tid; i < 64*16; i += 256) {
        int r = i >> 4, s = i & 15;
        *(uint4*)&Abuf[r][s*8] = *(const uint4*)&hc[(size_t)(m0+r)*DM + s*8];
    }
    for (int i = tid; i < 128*16; i += 256) {
        int r = i >> 4, s = i & 15;
        *(uint4*)&Wbuf[r][s*8] = *(const uint4*)&wbf[(size_t)(n0+r)*DM + s*8];
    }
    __syncthreads();
    const int lane = tid & 63, wv = tid >> 6, fr = lane & 15, q = lane >> 4;
    f32x4 acc[8];
    #pragma unroll
    for (int i = 0; i < 8; ++i) acc[i] = (f32x4){0.f,0.f,0.f,0.f};
    #pragma unroll
    for (int kt = 0; kt < 4; ++kt) {
        short8 af = *reinterpret_cast<const short8*>(&Abuf[wv*16 + fr][kt*32 + q*8]);
        #pragma unroll
        for (int ns = 0; ns < 8; ++ns) {
            short8 bf = *reinterpret_cast<const short8*>(&Wbuf[ns*16 + fr][kt*32 + q*8]);
            acc[ns] = __builtin_amdgcn_mfma_f32_16x16x32_bf16(af, bf, acc[ns], 0, 0, 0);
        }
    }
    #pragma unroll
    for (int r = 0; r < 4; ++r) {
        int m = m0 + wv*16 + q*4 + r;
        int b = m >> 11, l = m & 2047;
        size_t rowbase = (size_t)(l*NB + b)*HID + n0;
        #pragma unroll
        for (int ns = 0; ns < 8; ++ns) {
            int n = ns*16 + fr;
            out[rowbase + n] = acc[ns][r] + b_up[n0 + n] + x[rowbase + n];
        }
    }
}

// ---------------- K3: causal depthwise conv7 + bias + silu, one row per block.
// Threads 288..295 compute dt/dA (softplus+exp) and store TRANSPOSED
// [dir][h][b][scan_pos] so scan kernels load them as one coalesced row.
__global__ __launch_bounds__(320) void k_conv(const float* __restrict__ zx,
    const float* __restrict__ cw, const float* __restrict__ cb,
    const float* __restrict__ dt_bias, const float* __restrict__ A_log,
    float* __restrict__ xBC, float* __restrict__ dtbuf, float* __restrict__ dAbuf)
{
    const int m = blockIdx.x;
    const int l = m & (SEQL-1), b = m >> 11;
    const int c = threadIdx.x;
    if (c < CONV_DIM) {
        float acc = cb[c];
        #pragma unroll
        for (int k = 0; k < 7; ++k) {
            int l2 = l - 6 + k;
            if (l2 >= 0)
                acc = fmaf(zx[(size_t)(b*SEQL + l2)*DPROJ + DIN + c], cw[c*7 + k], acc);
        }
        xBC[(size_t)m*CONV_DIM + c] = siluf(acc);
    } else if (c < CONV_DIM + 2*NH) {
        int j = c - CONV_DIM;
        int dir = j >> 2, hh = j & 3;
        float dtraw = zx[(size_t)(b*SEQL + l)*DPROJ + 544 + j] + dt_bias[hh];
        float dt = dtraw > 20.f ? dtraw : log1pf(expf(dtraw));
        float dA = expf(dt * (-expf(A_log[hh])));
        int pos = dir ? (SEQL-1 - l) : l;
        size_t o = (size_t)((dir*NH + hh)*NB + b)*SEQL + pos;
        dtbuf[o] = dt; dAbuf[o] = dA;
    }
}

// ---------------- K4a: chunk-local scan states. 256 threads (4 waves),
// wave w owns p in [w*16, w*16+16); lane: pg=lane>>2 -> p, ng=lane&3 -> n-quad.
__global__ __launch_bounds__(256) void k_scan_state(const float* __restrict__ xBC,
    const float* __restrict__ dtbuf, const float* __restrict__ dAbuf,
    float* __restrict__ Sbuf, float* __restrict__ Pbuf)
{
    const int bid = blockIdx.x;
    const int c   = bid & (NCHUNK-1);
    const int h   = (bid >> 5) & (NH-1);
    const int b   = (bid >> 7) & 3;
    const int dir = bid >> 9;
    const int tid = threadIdx.x;
    __shared__ float dA_s[TCH], dt_s[TCH];
    __shared__ float Xs[TCH][HD];
    __shared__ float Bs[TCH][DST];
    const size_t tb = (size_t)((dir*NH + h)*NB + b)*SEQL + c*TCH;
    if (tid < TCH) {
        dt_s[tid] = dtbuf[tb + tid];
        dA_s[tid] = dAbuf[tb + tid];
    }
    __syncthreads();
    #pragma unroll
    for (int t = 0; t < 4; ++t) {
        int idx = t*256 + tid;
        int k2 = idx >> 4, p4 = (idx & 15)*4;
        int l2 = dir ? (SEQL-1 - (c*TCH + k2)) : (c*TCH + k2);
        float4 v = *(const float4*)&xBC[(size_t)(b*SEQL + l2)*CONV_DIM + h*HD + p4];
        float sc = dt_s[k2];
        v.x *= sc; v.y *= sc; v.z *= sc; v.w *= sc;
        *(float4*)&Xs[k2][p4] = v;
    }
    {
        int k2 = tid >> 2, n4 = (tid & 3)*4;
        int l2 = dir ? (SEQL-1 - (c*TCH + k2)) : (c*TCH + k2);
        *(float4*)&Bs[k2][n4] = *(const float4*)&xBC[(size_t)(b*SEQL + l2)*CONV_DIM + DIN + n4];
    }
    __syncthreads();
    const int lane = tid & 63, w = tid >> 6;
    const int p = w*16 + (lane >> 2), ng = lane & 3;
    float s[4] = {0.f, 0.f, 0.f, 0.f};
    for (int k2 = 0; k2 < TCH; ++k2) {
        float dAv = dA_s[k2];
        float xa  = Xs[k2][p];
        float4 bv = *(const float4*)&Bs[k2][ng*4];
        s[0] = fmaf(dAv, s[0], xa*bv.x);
        s[1] = fmaf(dAv, s[1], xa*bv.y);
        s[2] = fmaf(dAv, s[2], xa*bv.z);
        s[3] = fmaf(dAv, s[3], xa*bv.w);
    }
    const size_t sb = (size_t)bid * 1024;
    float4 sv = {s[0], s[1], s[2], s[3]};
    *(float4*)&Sbuf[sb + (size_t)(p*16 + ng*4)] = sv;
    if (w == 0) {   // wave-parallel product of 64 decays
        float pv = dA_s[lane];
        #pragma unroll
        for (int o = 32; o > 0; o >>= 1) pv *= __shfl_xor(pv, o, 64);
        if (lane == 0) Pbuf[bid] = pv;
    }
}

// ---------------- K4b: register-pipelined combine. 32768 independent chains.
__global__ __launch_bounds__(64) void k_scan_combine2(const float* __restrict__ Sbuf,
    const float* __restrict__ Pbuf, float* __restrict__ Hbuf)
{
    const int gt = blockIdx.x*64 + threadIdx.x;
    const int g = gt >> 10, e = gt & 1023;
    float sv[NCHUNK], pw[NCHUNK];
    #pragma unroll
    for (int cc = 0; cc < NCHUNK; ++cc)
        sv[cc] = Sbuf[(size_t)(g*NCHUNK + cc)*1024 + e];
    #pragma unroll
    for (int cc = 0; cc < NCHUNK; ++cc)
        pw[cc] = Pbuf[g*NCHUNK + cc];
    float carry = 0.f;
    #pragma unroll
    for (int cc = 0; cc < NCHUNK; ++cc) {
        Hbuf[(size_t)(g*NCHUNK + cc)*1024 + e] = carry;
        carry = fmaf(pw[cc], carry, sv[cc]);
    }
}

// ---------------- K4c: replay with correct init, emit y. Same layout as K4a.
__global__ __launch_bounds__(256) void k_scan_out(const float* __restrict__ xBC,
    const float* __restrict__ dtbuf, const float* __restrict__ dAbuf,
    const float* __restrict__ Hbuf, float* __restrict__ yfw, float* __restrict__ ybw)
{
    const int bid = blockIdx.x;
    const int c   = bid & (NCHUNK-1);
    const int h   = (bid >> 5) & (NH-1);
    const int b   = (bid >> 7) & 3;
    const int dir = bid >> 9;
    const int tid = threadIdx.x;
    __shared__ float dA_s[TCH], dt_s[TCH];
    __shared__ float Xs[TCH][HD];
    __shared__ float Bs[TCH][DST];
    __shared__ float Cs[TCH][DST];
    const size_t tb = (size_t)((dir*NH + h)*NB + b)*SEQL + c*TCH;
    if (tid < TCH) {
        dt_s[tid] = dtbuf[tb + tid];
        dA_s[tid] = dAbuf[tb + tid];
    }
    __syncthreads();
    #pragma unroll
    for (int t = 0; t < 4; ++t) {
        int idx = t*256 + tid;
        int k2 = idx >> 4, p4 = (idx & 15)*4;
        int l2 = dir ? (SEQL-1 - (c*TCH + k2)) : (c*TCH + k2);
        float4 v = *(const float4*)&xBC[(size_t)(b*SEQL + l2)*CONV_DIM + h*HD + p4];
        float sc = dt_s[k2];
        v.x *= sc; v.y *= sc; v.z *= sc; v.w *= sc;
        *(float4*)&Xs[k2][p4] = v;
    }
    {
        int k2 = tid >> 2, n4 = (tid & 3)*4;
        int l2 = dir ? (SEQL-1 - (c*TCH + k2)) : (c*TCH + k2);
        *(float4*)&Bs[k2][n4] = *(const float4*)&xBC[(size_t)(b*SEQL + l2)*CONV_DIM + DIN + n4];
        *(float4*)&Cs[k2][n4] = *(const float4*)&xBC[(size_t)(b*SEQL + l2)*CONV_DIM + DIN + DST + n4];
    }
    __syncthreads();
    const int lane = tid & 63, w = tid >> 6;
    const int p = w*16 + (lane >> 2), ng = lane & 3;
    const size_t hb = (size_t)bid * 1024;
    float4 hv = *(const float4*)&Hbuf[hb + (size_t)(p*16 + ng*4)];
    float s[4] = {hv.x, hv.y, hv.z, hv.w};
    float* yout = dir ? ybw : yfw;
    for (int k2 = 0; k2 < TCH; ++k2) {
        float dAv = dA_s[k2];
        float xa  = Xs[k2][p];
        float4 bv = *(const float4*)&Bs[k2][ng*4];
        float4 cv = *(const float4*)&Cs[k2][ng*4];
        s[0] = fmaf(dAv, s[0], xa*bv.x);
        s[1] = fmaf(dAv, s[1], xa*bv.y);
        s[2] = fmaf(dAv, s[2], xa*bv.z);
        s[3] = fmaf(dAv, s[3], xa*bv.w);
        float yp = s[0]*cv.x + s[1]*cv.y + s[2]*cv.z + s[3]*cv.w;
        yp += __shfl_xor(yp, 1, 64);
        yp += __shfl_xor(yp, 2, 64);
        if (ng == 0) {
            int l2 = dir ? (SEQL-1 - (c*TCH + k2)) : (c*TCH + k2);
            yout[(size_t)(b*SEQL + l2)*DIN + h*HD + p] = yp;
        }
    }
}

// ---------------- K5: shift-combine + D-skip + gate + RMSNorm -> yn (bf16)
__global__ __launch_bounds__(256) void k_epi(const float* __restrict__ zx,
    const float* __restrict__ xBC, const float* __restrict__ yfw,
    const float* __restrict__ ybw, const float* __restrict__ fcD_w,
    const float* __restrict__ Dv, const float* __restrict__ norm_w,
    __hip_bfloat16* __restrict__ ynbf)
{
    const int m = blockIdx.x;
    const int l = m & (SEQL-1);
    const int d = threadIdx.x;
    const int lane = d & 63, wave = d >> 6;
    __shared__ float red[4][4];
    __shared__ float redq[4];
    float xs = xBC[(size_t)m*CONV_DIM + d];
    float yv = 0.f;
    if (l > 0)       yv += yfw[(size_t)(m-1)*DIN + d];
    if (l < SEQL-1)  yv += ybw[(size_t)(m+1)*DIN + d];
    float p0 = wave_sum(xs * fcD_w[0*DIN + d]);
    float p1 = wave_sum(xs * fcD_w[1*DIN + d]);
    float p2 = wave_sum(xs * fcD_w[2*DIN + d]);
    float p3 = wave_sum(xs * fcD_w[3*DIN + d]);
    if (lane == 0) { red[wave][0]=p0; red[wave][1]=p1; red[wave][2]=p2; red[wave][3]=p3; }
    __syncthreads();
    const int h = d >> 6;
    float scal = red[0][h] + red[1][h] + red[2][h] + red[3][h] + Dv[h];
    yv = fmaf(xs, scal, yv);
    float z  = zx[(size_t)m*DPROJ + d];
    float yz = yv * siluf(z);
    float q = wave_sum(yz*yz);
    if (lane == 0) redq[wave] = q;
    __syncthreads();
    float ms = (redq[0] + redq[1] + redq[2] + redq[3]) * (1.f/DIN);
    float r = rsqrtf(ms + 1e-5f);
    ynbf[(size_t)m*DIN + d] = __float2bfloat16(yz * r * norm_w[d]);
}

extern "C" void kernel_launch(void* const* d_in, const int* in_sizes, int n_in,
                              void* d_out, int out_size, void* d_ws, size_t ws_size,
                              hipStream_t stream)
{
    const float* x       = (const float*)d_in[0];
    const float* w_down  = (const float*)d_in[1];
    const float* b_down  = (const float*)d_in[2];
    const float* w_up    = (const float*)d_in[3];
    const float* b_up    = (const float*)d_in[4];
    const float* gate1   = (const float*)d_in[5];
    const float* in_w    = (const float*)d_in[6];
    const float* conv_w  = (const float*)d_in[7];
    const float* conv_b  = (const float*)d_in[8];
    const float* dt_bias = (const float*)d_in[9];
    const float* A_log   = (const float*)d_in[10];
    const float* Dv      = (const float*)d_in[11];
    const float* fcD_w   = (const float*)d_in[12];
    const float* norm_w  = (const float*)d_in[13];
    const float* out_w   = (const float*)d_in[14];
    float* out = (float*)d_out;
    float* ws  = (float*)d_ws;

    size_t off = 0;
    float* xmid = ws + off; off += (size_t)MROWS*DM;
    float* zx   = ws + off; off += (size_t)MROWS*DPROJ;
    float* xBC  = ws + off; off += (size_t)MROWS*CONV_DIM;
    float* yfw  = ws + off; off += (size_t)MROWS*DIN;
    float* ybw  = ws + off; off += (size_t)MROWS*DIN;
    float* Sbuf = ws + off; off += (size_t)1024*1024;
    float* Pbuf = ws + off; off += 1024;
    float* Hbuf = ws + off; off += (size_t)1024*1024;
    float* dtbuf= ws + off; off += (size_t)2*NH*NB*SEQL;
    float* dAbuf= ws + off; off += (size_t)2*NH*NB*SEQL;
    __hip_bfloat16* bfb = (__hip_bfloat16*)(ws + off);
    size_t bo = 0;
    __hip_bfloat16* wd_bf = bfb + bo; bo += 524288;
    __hip_bfloat16* wu_bf = bfb + bo; bo += 524288;
    __hip_bfloat16* wi_bf = bfb + bo; bo += 71680;
    __hip_bfloat16* wo_bf = bfb + bo; bo += 32768;
    __hip_bfloat16* u_bf  = bfb + bo; bo += (size_t)MROWS*DM;
    __hip_bfloat16* yn_bf = bfb + bo; bo += (size_t)MROWS*DIN;
    __hip_bfloat16* hc_bf = bfb + bo; bo += (size_t)MROWS*DM;
    float* partial = zx;   // alias: 4*MROWS*DM = 4.19M floats <= MROWS*552 = 4.52M

    k_prep_w<<<4504, 256, 0, stream>>>(w_down, w_up, in_w, out_w, wd_bf, wu_bf, wi_bf, wo_bf);

    dim3 gdown(MROWS/64, KSPLIT);
    k_down_mfma<<<gdown, 256, 0, stream>>>(x, wd_bf, partial);
    k_down_fix<<<MROWS*DM/1024, 256, 0, stream>>>(partial, b_down, xmid, u_bf);

    for (int pass = 0; pass < 2; ++pass) {
        dim3 gin(MROWS/64, 7);
        k_proj_in<<<gin, 256, 0, stream>>>(u_bf, wi_bf, zx);
        k_conv<<<MROWS, 320, 0, stream>>>(zx, conv_w, conv_b, dt_bias, A_log, xBC, dtbuf, dAbuf);
        k_scan_state<<<1024, 256, 0, stream>>>(xBC, dtbuf, dAbuf, Sbuf, Pbuf);
        k_scan_combine2<<<512, 64, 0, stream>>>(Sbuf, Pbuf, Hbuf);
        k_scan_out<<<1024, 256, 0, stream>>>(xBC, dtbuf, dAbuf, Hbuf, yfw, ybw);
        k_epi<<<MROWS, 256, 0, stream>>>(zx, xBC, yfw, ybw, fcD_w, Dv, norm_w, yn_bf);
        if (pass == 0)
            k_proj_out_t<0><<<MROWS/64, 256, 0, stream>>>(yn_bf, wo_bf, xmid, gate1, u_bf, hc_bf);
        else
            k_proj_out_t<1><<<MROWS/64, 256, 0, stream>>>(yn_bf, wo_bf, xmid, gate1, u_bf, hc_bf);
    }

    dim3 gup(MROWS/64, HID/128);
    k_up_mfma<<<gup, 256, 0, stream>>>(hc_bf, wu_bf, b_up, x, out);
}